// Round 5
// baseline (163.048 us; speedup 1.0000x reference)
//
#include <hip/hip_runtime.h>

#define NROWS 2048
#define KDIM  768
#define L     40
#define KC    96          // K per chunk; 768 = 8 * 96
#define NKC   8
#define HN    (NROWS * L)
#define NBLK  512         // total blocks; all co-resident (2/CU on 256 CUs)
#define BI 128
#define BJ 64
#define STRD 44

// ---------------------------------------------------------------------------
// Single fused persistent kernel, 512 blocks x 256 threads.
// Phase A: partial projections (rb = blk&63 rowblock, kc = blk>>6 K-chunk),
//          register-blocked, wave-uniform W via readfirstlane (scalar pipe),
//          A-tile in LDS transposed + xor-swizzled (conflict-free).
//          Writes part[(kc*40+o)*4096 + which*2048 + row] (coalesced).
// Device barrier: agent-scope ticket (all 512 blocks resident by
//          __launch_bounds__(256,2): LDS 34KB, VGPR ~110 -> >=2 blocks/CU).
//          Release publishes part across XCDs; acquire invalidates caches.
// Phase B: pairwise tile (bi = blk&15 -> i0, bj = blk>>4 -> j0); staging
//          folds the 8-chunk partial reduction (L2-hit reads) + b1 fold,
//          then 8x4 micro-tile relu-dot, exp-sum, diagonal T0, finalize by
//          last-finishing block (second ticket).
// ---------------------------------------------------------------------------
__global__ __launch_bounds__(256, 2) void k_fused(const float* __restrict__ x,
                                                  const float* __restrict__ y,
                                                  const float* __restrict__ W1,
                                                  const float* __restrict__ b1,
                                                  const float* __restrict__ W2,
                                                  const float* __restrict__ b2p,
                                                  float* __restrict__ part,
                                                  float* __restrict__ sums,
                                                  float* __restrict__ out) {
    __shared__ union U {
        float A[KC * 64];                                   // 24 KB
        struct {
            float sy[BI * STRD];                            // 22.5 KB
            float sx[BJ * STRD];                            // 11.3 KB
            float w2[STRD];
            float red[8];
        } B;                                                // 33.9 KB
    } sh;

    const int tid = threadIdx.x;
    const int blk = blockIdx.x;

    // ---------------- Phase A: partial projections ----------------
    {
        const int rb  = blk & 63;             // 0-31: x, 32-63: y
        const int kc  = blk >> 6;             // 0..7
        const int k0  = kc * KC;
        const int which = rb >> 5;
        const float* __restrict__ A = which ? y : x;
        const int r0 = (rb & 31) * 64;

#pragma unroll
        for (int p = 0; p < 6; ++p) {
            int idx = tid + p * 256;
            int row = idx / 24;
            int kk4 = idx - row * 24;         // 0..23
            float4 v = *(const float4*)(A + (size_t)(r0 + row) * KDIM + k0 + kk4 * 4);
            int rowx = row ^ kk4;             // xor swizzle
            sh.A[(kk4 * 4 + 0) * 64 + rowx] = v.x;
            sh.A[(kk4 * 4 + 1) * 64 + rowx] = v.y;
            sh.A[(kk4 * 4 + 2) * 64 + rowx] = v.z;
            sh.A[(kk4 * 4 + 3) * 64 + rowx] = v.w;
        }
        __syncthreads();

        const int row = tid & 63;
        const int og  = __builtin_amdgcn_readfirstlane(tid >> 6);  // wave-uniform
        const float* wbase = W1 + (size_t)which * KDIM
                                + (size_t)(og * 10) * (2 * KDIM) + k0;
        float acc[10];
#pragma unroll
        for (int oi = 0; oi < 10; ++oi) acc[oi] = 0.f;

#pragma unroll
        for (int k4 = 0; k4 < 24; ++k4) {
            int rowx = row ^ k4;
            float a0 = sh.A[(k4 * 4 + 0) * 64 + rowx];
            float a1 = sh.A[(k4 * 4 + 1) * 64 + rowx];
            float a2 = sh.A[(k4 * 4 + 2) * 64 + rowx];
            float a3 = sh.A[(k4 * 4 + 3) * 64 + rowx];
#pragma unroll
            for (int oi = 0; oi < 10; ++oi) {
                float4 w = *(const float4*)(wbase + (size_t)oi * (2 * KDIM) + k4 * 4);
                acc[oi] += a0 * w.x + a1 * w.y + a2 * w.z + a3 * w.w;
            }
        }

        float* po = part + ((size_t)kc * L + og * 10) * 4096 + rb * 64 + row;
#pragma unroll
        for (int oi = 0; oi < 10; ++oi) po[(size_t)oi * 4096] = acc[oi];
    }

    // ---------------- Device-scope barrier (all 512 blocks resident) --------
    __syncthreads();   // drains each wave's vmem (compiler emits vmcnt(0))
    if (tid == 0) {
        unsigned* bar = (unsigned*)sums + 3;
        __hip_atomic_fetch_add(bar, 1u, __ATOMIC_ACQ_REL, __HIP_MEMORY_SCOPE_AGENT);
        while (__hip_atomic_load(bar, __ATOMIC_ACQUIRE, __HIP_MEMORY_SCOPE_AGENT) < NBLK)
            __builtin_amdgcn_s_sleep(2);
    }
    __syncthreads();

    // ---------------- Phase B: pairwise tile ----------------
    {
        const int i0 = (blk & 15) * BI;
        const int j0 = (blk >> 4) * BJ;

        // stage i-tile from hy partials (which=1), reducing 8 K-chunks
        for (int idx = tid; idx < BI * L; idx += 256) {
            int row = idx & 127;
            int o   = idx >> 7;
            const float* p = part + ((size_t)o << 12) + 2048 + i0 + row;
            float s = 0.f;
#pragma unroll
            for (int kc = 0; kc < NKC; ++kc) s += p[(size_t)kc * (L << 12)];
            sh.B.sy[row * STRD + o] = s;
        }
        // stage j-tile from hx partials (which=0), + b1 fold
        for (int idx = tid; idx < BJ * L; idx += 256) {
            int row = idx & 63;
            int o   = idx >> 6;
            const float* p = part + ((size_t)o << 12) + j0 + row;
            float s = b1[o];
#pragma unroll
            for (int kc = 0; kc < NKC; ++kc) s += p[(size_t)kc * (L << 12)];
            sh.B.sx[row * STRD + o] = s;
        }
        if (tid < 10) ((float4*)sh.B.w2)[tid] = ((const float4*)W2)[tid];
        __syncthreads();

        const int tx = tid & 15, ty = tid >> 4;

        float acc[8][4];
#pragma unroll
        for (int u = 0; u < 8; ++u)
#pragma unroll
            for (int v = 0; v < 4; ++v) acc[u][v] = 0.f;

#pragma unroll
        for (int k4 = 0; k4 < 10; ++k4) {
            float4 w = *(const float4*)(sh.B.w2 + k4 * 4);
            float4 ay[8], ax[4];
#pragma unroll
            for (int u = 0; u < 8; ++u)
                ay[u] = *(const float4*)(sh.B.sy + (ty + 16 * u) * STRD + k4 * 4);
#pragma unroll
            for (int v = 0; v < 4; ++v)
                ax[v] = *(const float4*)(sh.B.sx + (tx + 16 * v) * STRD + k4 * 4);
#pragma unroll
            for (int u = 0; u < 8; ++u)
#pragma unroll
                for (int v = 0; v < 4; ++v) {
                    float t;
                    t = ay[u].x + ax[v].x; t = fmaxf(t, 0.f); acc[u][v] += t * w.x;
                    t = ay[u].y + ax[v].y; t = fmaxf(t, 0.f); acc[u][v] += t * w.y;
                    t = ay[u].z + ax[v].z; t = fmaxf(t, 0.f); acc[u][v] += t * w.z;
                    t = ay[u].w + ax[v].w; t = fmaxf(t, 0.f); acc[u][v] += t * w.w;
                }
        }

        const float b2v = b2p[0];
        float sumE = 0.f, sumT = 0.f;
#pragma unroll
        for (int u = 0; u < 8; ++u)
#pragma unroll
            for (int v = 0; v < 4; ++v) {
                int gi = i0 + ty + 16 * u;
                int gj = j0 + tx + 16 * v;
                float val = acc[u][v] + b2v;
                if (gi == gj) sumT += val;
                sumE += __expf(val - 1.f);
            }

#pragma unroll
        for (int off = 32; off > 0; off >>= 1) {
            sumE += __shfl_down(sumE, off);
            sumT += __shfl_down(sumT, off);
        }
        int wid = tid >> 6;
        if ((tid & 63) == 0) { sh.B.red[wid] = sumE; sh.B.red[4 + wid] = sumT; }
        __syncthreads();
        if (tid == 0) {
            float e = sh.B.red[0] + sh.B.red[1] + sh.B.red[2] + sh.B.red[3];
            float t = sh.B.red[4] + sh.B.red[5] + sh.B.red[6] + sh.B.red[7];
            atomicAdd(&sums[1], e);
            atomicAdd(&sums[0], t);
            __threadfence();
            unsigned done = atomicAdd(((unsigned*)sums) + 2, 1u);
            if (done == NBLK - 1) {
                float T = atomicAdd(&sums[0], 0.0f);   // coherent read-back
                float E = atomicAdd(&sums[1], 0.0f);
                const float invN = 1.0f / (float)NROWS;
                out[0] = T * invN - E * invN * invN;
            }
        }
    }
}

extern "C" void kernel_launch(void* const* d_in, const int* in_sizes, int n_in,
                              void* d_out, int out_size, void* d_ws, size_t ws_size,
                              hipStream_t stream) {
    const float* x  = (const float*)d_in[0];
    const float* y  = (const float*)d_in[1];
    const float* W1 = (const float*)d_in[2];
    const float* b1 = (const float*)d_in[3];
    const float* W2 = (const float*)d_in[4];
    const float* b2 = (const float*)d_in[5];
    float* out = (float*)d_out;

    float* wsf  = (float*)d_ws;
    float* sums = wsf;                 // [0]=T0,[1]=E,[2]=finalize,[3]=barrier
    float* part = wsf + 16;            // 8 * 40 * 4096 partials

    hipMemsetAsync(sums, 0, 16, stream);   // zero sums + both tickets
    k_fused<<<NBLK, 256, 0, stream>>>(x, y, W1, b1, W2, b2, part, sums, out);
}

// Round 6
// 116.499 us; speedup vs baseline: 1.3996x; 1.3996x over previous
//
#include <hip/hip_runtime.h>

#define NROWS 2048
#define KDIM  768
#define L     40
#define KC    96          // K per chunk; 768 = 8 * 96
#define NKC   8
#define HN    (NROWS * L)
#define NPAIRBLK 512      // k_pair grid (16 x 32)
#define BI 128
#define BJ 64
#define STRD 44

// ---------------------------------------------------------------------------
// Kernel 1: partial projections, register-blocked (proven R4 version).
// grid (64 rowblocks, 8 kchunks), block 256 = 64 rows(lanes) x 4 waves.
// Wave-uniform W via readfirstlane -> scalar-pipe s_loads; A-tile in LDS
// transposed + xor-swizzled (conflict-free). Partials [kc][o][row] coalesced.
// ---------------------------------------------------------------------------
__global__ __launch_bounds__(256) void k_proj(const float* __restrict__ x,
                                              const float* __restrict__ y,
                                              const float* __restrict__ W1,
                                              float* __restrict__ part) {
    __shared__ float shA[KC * 64];          // 24 KB
    const int tid = threadIdx.x;
    const int rb  = blockIdx.x;             // 0-31: x, 32-63: y
    const int kc  = blockIdx.y;             // 0..7
    const int k0  = kc * KC;
    const int which = rb >> 5;
    const float* __restrict__ A = which ? y : x;
    const int r0 = (rb & 31) * 64;

#pragma unroll
    for (int p = 0; p < 6; ++p) {
        int idx = tid + p * 256;
        int row = idx / 24;
        int kk4 = idx - row * 24;           // 0..23
        float4 v = *(const float4*)(A + (size_t)(r0 + row) * KDIM + k0 + kk4 * 4);
        int rowx = row ^ kk4;
        shA[(kk4 * 4 + 0) * 64 + rowx] = v.x;
        shA[(kk4 * 4 + 1) * 64 + rowx] = v.y;
        shA[(kk4 * 4 + 2) * 64 + rowx] = v.z;
        shA[(kk4 * 4 + 3) * 64 + rowx] = v.w;
    }
    __syncthreads();

    const int row = tid & 63;
    const int og  = __builtin_amdgcn_readfirstlane(tid >> 6);   // wave-uniform
    const float* wbase = W1 + (size_t)which * KDIM
                            + (size_t)(og * 10) * (2 * KDIM) + k0;

    float acc[10];
#pragma unroll
    for (int oi = 0; oi < 10; ++oi) acc[oi] = 0.f;

#pragma unroll
    for (int k4 = 0; k4 < 24; ++k4) {
        int rowx = row ^ k4;
        float a0 = shA[(k4 * 4 + 0) * 64 + rowx];
        float a1 = shA[(k4 * 4 + 1) * 64 + rowx];
        float a2 = shA[(k4 * 4 + 2) * 64 + rowx];
        float a3 = shA[(k4 * 4 + 3) * 64 + rowx];
#pragma unroll
        for (int oi = 0; oi < 10; ++oi) {
            float4 w = *(const float4*)(wbase + (size_t)oi * (2 * KDIM) + k4 * 4);
            acc[oi] += a0 * w.x + a1 * w.y + a2 * w.z + a3 * w.w;
        }
    }

    float* po = part + ((size_t)kc * L + og * 10) * 4096 + rb * 64 + row;
#pragma unroll
    for (int oi = 0; oi < 10; ++oi) po[(size_t)oi * 4096] = acc[oi];
}

// ---------------------------------------------------------------------------
// Kernel 1b: reduce 8 K-chunk partials -> hxb / hy (proven R4 version).
// Block 0 zeroes sums + finalize ticket (no memset node needed).
// ---------------------------------------------------------------------------
__global__ __launch_bounds__(256) void k_red(const float* __restrict__ part,
                                             float* __restrict__ hxb,
                                             float* __restrict__ hy,
                                             float* __restrict__ sums) {
    __shared__ float shT[64 * 41];
    const int tid = threadIdx.x;
    const int rb  = blockIdx.x;             // 0..63
    if (rb == 0 && tid == 0) {
        sums[0] = 0.f; sums[1] = 0.f;
        ((unsigned*)sums)[2] = 0u;
    }
    const int row = tid & 63;
    const int og  = tid >> 6;

    float s[10];
#pragma unroll
    for (int oi = 0; oi < 10; ++oi) s[oi] = 0.f;
    const float* pb = part + (size_t)(og * 10) * 4096 + rb * 64 + row;
#pragma unroll
    for (int kc = 0; kc < NKC; ++kc)
#pragma unroll
        for (int oi = 0; oi < 10; ++oi)
            s[oi] += pb[((size_t)kc * L + oi) * 4096];

#pragma unroll
    for (int oi = 0; oi < 10; ++oi) shT[row * 41 + og * 10 + oi] = s[oi];
    __syncthreads();

    float* out = (rb < 32) ? (hxb + (size_t)rb * 64 * L)
                           : (hy  + (size_t)(rb - 32) * 64 * L);
    for (int idx = tid; idx < 64 * L; idx += 256) {
        int r = idx / L, o = idx - r * L;
        out[idx] = shT[r * 41 + o];
    }
}

// ---------------------------------------------------------------------------
// Kernel 2: pairwise relu-dot + exp-sum + diag T0 + finalize.
// SPILL-FREE REBUILD: float2 k-steps (live ~70 VGPRs: acc32+ay16+ax8+w2+addr),
// __launch_bounds__(256,4) -> 128-VGPR budget, no full unroll (unroll 2).
// Tile BI=128 x BJ=64, block 256 = 16(ty) x 16(tx), micro-tile 8x4.
// LDS b64 reads: ay = 4 addrs x16-lane broadcast (conflict-free),
// ax = 2-way aliased (free per m136).
// ---------------------------------------------------------------------------
__global__ __launch_bounds__(256, 4) void k_pair(const float* __restrict__ hxb,
                                                 const float* __restrict__ hy,
                                                 const float* __restrict__ W2,
                                                 const float* __restrict__ b1,
                                                 const float* __restrict__ b2p,
                                                 float* __restrict__ sums,
                                                 float* __restrict__ out) {
    __shared__ float shy[BI * STRD];
    __shared__ float shx[BJ * STRD];
    __shared__ float sw2[STRD];
    __shared__ float red[8];

    const int tid = threadIdx.x;
    const int i0 = blockIdx.x * BI;
    const int j0 = blockIdx.y * BJ;

    for (int idx = tid; idx < BI * 10; idx += 256) {
        int rr = idx / 10, c = idx - rr * 10;
        float4 v = ((const float4*)(hy + (size_t)i0 * L))[idx];
        *(float4*)(shy + rr * STRD + c * 4) = v;
    }
    for (int idx = tid; idx < BJ * 10; idx += 256) {
        int rr = idx / 10, c = idx - rr * 10;
        float4 v = ((const float4*)(hxb + (size_t)j0 * L))[idx];
        float4 bv = ((const float4*)b1)[c];
        v.x += bv.x; v.y += bv.y; v.z += bv.z; v.w += bv.w;
        *(float4*)(shx + rr * STRD + c * 4) = v;
    }
    if (tid < 10) ((float4*)sw2)[tid] = ((const float4*)W2)[tid];
    __syncthreads();

    const int tx = tid & 15, ty = tid >> 4;

    float acc[8][4];
#pragma unroll
    for (int u = 0; u < 8; ++u)
#pragma unroll
        for (int v = 0; v < 4; ++v) acc[u][v] = 0.f;

#pragma unroll 2
    for (int k2 = 0; k2 < 20; ++k2) {
        float2 w = *(const float2*)(sw2 + k2 * 2);
        float2 ay[8], ax[4];
#pragma unroll
        for (int u = 0; u < 8; ++u)
            ay[u] = *(const float2*)(shy + (ty + 16 * u) * STRD + k2 * 2);
#pragma unroll
        for (int v = 0; v < 4; ++v)
            ax[v] = *(const float2*)(shx + (tx + 16 * v) * STRD + k2 * 2);
#pragma unroll
        for (int u = 0; u < 8; ++u)
#pragma unroll
            for (int v = 0; v < 4; ++v) {
                float t;
                t = ay[u].x + ax[v].x; t = fmaxf(t, 0.f); acc[u][v] += t * w.x;
                t = ay[u].y + ax[v].y; t = fmaxf(t, 0.f); acc[u][v] += t * w.y;
            }
    }

    const float b2v = b2p[0];
    float sumE = 0.f, sumT = 0.f;
#pragma unroll
    for (int u = 0; u < 8; ++u)
#pragma unroll
        for (int v = 0; v < 4; ++v) {
            int gi = i0 + ty + 16 * u;
            int gj = j0 + tx + 16 * v;
            float val = acc[u][v] + b2v;
            if (gi == gj) sumT += val;
            sumE += __expf(val - 1.f);
        }

#pragma unroll
    for (int off = 32; off > 0; off >>= 1) {
        sumE += __shfl_down(sumE, off);
        sumT += __shfl_down(sumT, off);
    }
    int wid = tid >> 6;
    if ((tid & 63) == 0) { red[wid] = sumE; red[4 + wid] = sumT; }
    __syncthreads();
    if (tid == 0) {
        float e = red[0] + red[1] + red[2] + red[3];
        float t = red[4] + red[5] + red[6] + red[7];
        atomicAdd(&sums[1], e);
        atomicAdd(&sums[0], t);
        __threadfence();
        unsigned done = atomicAdd(((unsigned*)sums) + 2, 1u);
        if (done == NPAIRBLK - 1) {
            float T = atomicAdd(&sums[0], 0.0f);
            float E = atomicAdd(&sums[1], 0.0f);
            const float invN = 1.0f / (float)NROWS;
            out[0] = T * invN - E * invN * invN;
        }
    }
}

extern "C" void kernel_launch(void* const* d_in, const int* in_sizes, int n_in,
                              void* d_out, int out_size, void* d_ws, size_t ws_size,
                              hipStream_t stream) {
    const float* x  = (const float*)d_in[0];
    const float* y  = (const float*)d_in[1];
    const float* W1 = (const float*)d_in[2];
    const float* b1 = (const float*)d_in[3];
    const float* W2 = (const float*)d_in[4];
    const float* b2 = (const float*)d_in[5];
    float* out = (float*)d_out;

    float* wsf  = (float*)d_ws;
    float* sums = wsf;                 // [0]=T0,[1]=E,[2]=ticket
    float* hxb  = wsf + 16;            // 2048*40 (x-proj; b1 folded in k_pair)
    float* hy   = hxb + HN;            // 2048*40
    float* part = hy + HN;             // 8*40*4096

    k_proj<<<dim3(64, NKC), 256, 0, stream>>>(x, y, W1, part);
    k_red<<<64, 256, 0, stream>>>(part, hxb, hy, sums);
    k_pair<<<dim3(NROWS / BI, NROWS / BJ), 256, 0, stream>>>(hxb, hy, W2, b1, b2,
                                                             sums, out);
}